// Round 1
// baseline (1006.341 us; speedup 1.0000x reference)
//
#include <hip/hip_runtime.h>

// H2GCNConv: out[:, 0:64]  = segment_sum(adj1_val * x[adj1_col], adj1_row)
//            out[:, 64:128]= segment_sum(adj2_val * x[adj2_col], adj2_row)
// N=100000, D=64 (== wave width), E1=1.6M, E2=3.2M, fp32.
//
// v1 strategy: one 64-lane wave per edge, lane d handles feature d.
// x[col*64 + lane] is a coalesced 256B wave read; x (25.6MB) is L3-resident.
// Scatter via global f32 atomicAdd into out[row*128 + col_off + lane].

#define NFEAT 64
#define OUT_STRIDE 128

__global__ __launch_bounds__(256) void spmm_scatter_kernel(
    const int* __restrict__ row, const int* __restrict__ col,
    const float* __restrict__ val, const float* __restrict__ x,
    float* __restrict__ out, int nedges, int col_off) {
  const int lane = threadIdx.x & 63;
  const int wid = (blockIdx.x * blockDim.x + threadIdx.x) >> 6;
  const int nwaves = (gridDim.x * blockDim.x) >> 6;

  for (int e = wid; e < nedges; e += nwaves) {
    // Wave-uniform scalar loads (same address across all 64 lanes -> one
    // transaction, broadcast).
    const int r = row[e];
    const int c = col[e];
    const float v = val[e];
    // Coalesced 256B gather of one x-row.
    const float xv = x[(long)c * NFEAT + lane];
    atomicAdd(&out[(long)r * OUT_STRIDE + col_off + lane], v * xv);
  }
}

extern "C" void kernel_launch(void* const* d_in, const int* in_sizes, int n_in,
                              void* d_out, int out_size, void* d_ws, size_t ws_size,
                              hipStream_t stream) {
  const float* x        = (const float*)d_in[0];
  const int*   adj1_row = (const int*)d_in[1];
  const int*   adj1_col = (const int*)d_in[2];
  const float* adj1_val = (const float*)d_in[3];
  const int*   adj2_row = (const int*)d_in[4];
  const int*   adj2_col = (const int*)d_in[5];
  const float* adj2_val = (const float*)d_in[6];

  const int e1 = in_sizes[1];
  const int e2 = in_sizes[4];

  float* out = (float*)d_out;

  // Zero the accumulator output (harness poisons 0xAA; atomics accumulate).
  hipMemsetAsync(d_out, 0, (size_t)out_size * sizeof(float), stream);

  // Grid-stride: ~16K waves resident-capacity is 8192 (256 CU x 32 waves),
  // give each wave a few hundred edges.
  const int block = 256;               // 4 waves per block
  const int grid = 4096;               // 16384 waves

  spmm_scatter_kernel<<<grid, block, 0, stream>>>(
      adj1_row, adj1_col, adj1_val, x, out, e1, /*col_off=*/0);
  spmm_scatter_kernel<<<grid, block, 0, stream>>>(
      adj2_row, adj2_col, adj2_val, x, out, e2, /*col_off=*/NFEAT);
}